// Round 6
// baseline (201.681 us; speedup 1.0000x reference)
//
#include <hip/hip_runtime.h>
#include <hip/hip_cooperative_groups.h>

namespace cg = cooperative_groups;

#define NBINS 256
#define BATCH 32
#define HW (512 * 512)
#define NSUB 4                 // per-wave sub-histograms (256 threads = 4 waves)
#define BLOCKS_PER_SAMPLE 32
#define NBLOCKS (BATCH * BLOCKS_PER_SAMPLE)  // 1024: 4 blocks/CU, co-resident

// Packed fixed-point histogram cell:
//   bits [0:43]  : sum of illum * 2^24   (global per-bin max 2^42)
//   bits [44:63] : count                 (global per-bin max 2^18)
#define CNT_SHIFT 44
#define SUM_MASK ((1ull << CNT_SHIFT) - 1)
#define FIX_SCALE 16777216.0f  // 2^24

__global__ __launch_bounds__(256) void fused_kernel(
    const float* __restrict__ img,          // [B,3,H,W]
    const float* __restrict__ depth,        // [B,1,H,W]
    unsigned long long* __restrict__ hist,  // [B,NBINS] packed
    float* __restrict__ out)
{
    __shared__ unsigned long long s_hist[NSUB][NBINS];  // 8 KB
    __shared__ float wsum[4];

    cg::grid_group grid = cg::this_grid();

    const int tid  = threadIdx.x;
    const int wave = tid >> 6;
    const int gid  = blockIdx.x * 256 + tid;

    // ---- phase 0: zero global hist (replaces hipMemsetAsync dispatch) ----
    if (gid < BATCH * NBINS) hist[gid] = 0ull;

    // zero LDS sub-histograms
    for (int i = tid; i < NSUB * NBINS; i += 256)
        ((unsigned long long*)s_hist)[i] = 0ull;

    grid.sync();

    // ---- phase 1: histogram ----
    const int b     = blockIdx.x / BLOCKS_PER_SAMPLE;
    const int chunk = blockIdx.x % BLOCKS_PER_SAMPLE;
    const int pixPerBlock = HW / BLOCKS_PER_SAMPLE;  // 8192
    const int base = chunk * pixPerBlock;

    const float4* Rp = (const float4*)(img + (size_t)b * 3 * HW + 0 * HW + base);
    const float4* Gp = (const float4*)(img + (size_t)b * 3 * HW + 1 * HW + base);
    const float4* Bp = (const float4*)(img + (size_t)b * 3 * HW + 2 * HW + base);
    const float4* Dp = (const float4*)(depth + (size_t)b * HW + base);

    const int nvec = pixPerBlock / 4;  // 2048 float4s per block
    for (int i = tid; i < nvec; i += 256) {
        float4 r  = Rp[i];
        float4 g  = Gp[i];
        float4 bl = Bp[i];
        float4 d  = Dp[i];

        float il0 = 0.2f * r.x + 0.7f * g.x + 0.1f * bl.x;
        float il1 = 0.2f * r.y + 0.7f * g.y + 0.1f * bl.y;
        float il2 = 0.2f * r.z + 0.7f * g.z + 0.1f * bl.z;
        float il3 = 0.2f * r.w + 0.7f * g.w + 0.1f * bl.w;

        int k0 = (int)(d.x * 255.0f + 0.5f);
        int k1 = (int)(d.y * 255.0f + 0.5f);
        int k2 = (int)(d.z * 255.0f + 0.5f);
        int k3 = (int)(d.w * 255.0f + 0.5f);
        k0 = min(max(k0, 0), NBINS - 1);
        k1 = min(max(k1, 0), NBINS - 1);
        k2 = min(max(k2, 0), NBINS - 1);
        k3 = min(max(k3, 0), NBINS - 1);

        unsigned long long v0 = (1ull << CNT_SHIFT) | (unsigned long long)(unsigned int)(il0 * FIX_SCALE + 0.5f);
        unsigned long long v1 = (1ull << CNT_SHIFT) | (unsigned long long)(unsigned int)(il1 * FIX_SCALE + 0.5f);
        unsigned long long v2 = (1ull << CNT_SHIFT) | (unsigned long long)(unsigned int)(il2 * FIX_SCALE + 0.5f);
        unsigned long long v3 = (1ull << CNT_SHIFT) | (unsigned long long)(unsigned int)(il3 * FIX_SCALE + 0.5f);

        atomicAdd(&s_hist[wave][k0], v0);
        atomicAdd(&s_hist[wave][k1], v1);
        atomicAdd(&s_hist[wave][k2], v2);
        atomicAdd(&s_hist[wave][k3], v3);
    }
    __syncthreads();

    // fold sub-histograms, one global packed atomic per bin per block
    for (int k = tid; k < NBINS; k += 256) {
        unsigned long long v = s_hist[0][k] + s_hist[1][k] + s_hist[2][k] + s_hist[3][k];
        atomicAdd(&hist[b * NBINS + k], v);
    }

    grid.sync();

    // ---- phase 2: loss on block 0 (deterministic, no extra LDS) ----
    if (blockIdx.x == 0) {
        float acc = 0.0f;
        const int k = tid;  // bin index, 0..255
        if (k < NBINS - 1) {
            for (int bb = 0; bb < BATCH; ++bb) {
                unsigned long long v0 = hist[bb * NBINS + k];
                unsigned long long v1 = hist[bb * NBINS + k + 1];
                float m0 = ((float)(v0 & SUM_MASK) * (1.0f / FIX_SCALE)) / (float)(unsigned int)(v0 >> CNT_SHIFT);
                float m1 = ((float)(v1 & SUM_MASK) * (1.0f / FIX_SCALE)) / (float)(unsigned int)(v1 >> CNT_SHIFT);
                acc += fmaxf(m0 - m1, 0.0f);
            }
        }
        for (int off = 32; off > 0; off >>= 1)
            acc += __shfl_down(acc, off, 64);
        if ((tid & 63) == 0) wsum[tid >> 6] = acc;
        __syncthreads();
        if (tid == 0)
            out[0] = (wsum[0] + wsum[1] + wsum[2] + wsum[3]) / (255.0f * (float)BATCH);
    }
}

extern "C" void kernel_launch(void* const* d_in, const int* in_sizes, int n_in,
                              void* d_out, int out_size, void* d_ws, size_t ws_size,
                              hipStream_t stream)
{
    const float* img   = (const float*)d_in[0];
    const float* depth = (const float*)d_in[1];
    float* out = (float*)d_out;
    unsigned long long* hist = (unsigned long long*)d_ws;

    void* args[] = { (void*)&img, (void*)&depth, (void*)&hist, (void*)&out };
    hipLaunchCooperativeKernel((void*)fused_kernel, dim3(NBLOCKS), dim3(256),
                               args, 0, stream);
}

// Round 7
// 49.351 us; speedup vs baseline: 4.0866x; 4.0866x over previous
//
#include <hip/hip_runtime.h>

#define NBINS 256
#define BATCH 32
#define HW (512 * 512)
#define NSUB 4                // per-wave sub-histograms (256 threads = 4 waves)
#define BLOCKS_PER_SAMPLE 64
#define CELL_STRIDE 8         // u64 per (b,bin) cell -> 64B = 1 cache line each

// Packed fixed-point histogram cell:
//   bits [0:43]  : sum of illum * 2^24   (global per-bin max 2^42)
//   bits [44:63] : count                 (global per-bin max 2^18)
#define CNT_SHIFT 44
#define SUM_MASK ((1ull << CNT_SHIFT) - 1)
#define FIX_SCALE 16777216.0f  // 2^24

__global__ __launch_bounds__(256) void hist_kernel(
    const float* __restrict__ img,          // [B,3,H,W]
    const float* __restrict__ depth,        // [B,1,H,W]
    unsigned long long* __restrict__ hist)  // [B*NBINS*CELL_STRIDE] padded
{
    __shared__ unsigned long long s_hist[NSUB][NBINS];  // 8 KB

    const int tid  = threadIdx.x;
    const int wave = tid >> 6;

    for (int i = tid; i < NSUB * NBINS; i += 256)
        ((unsigned long long*)s_hist)[i] = 0ull;
    __syncthreads();

    const int b     = blockIdx.x / BLOCKS_PER_SAMPLE;
    const int chunk = blockIdx.x % BLOCKS_PER_SAMPLE;
    const int pixPerBlock = HW / BLOCKS_PER_SAMPLE;  // 4096
    const int base = chunk * pixPerBlock;

    const float4* Rp = (const float4*)(img + (size_t)b * 3 * HW + 0 * HW + base);
    const float4* Gp = (const float4*)(img + (size_t)b * 3 * HW + 1 * HW + base);
    const float4* Bp = (const float4*)(img + (size_t)b * 3 * HW + 2 * HW + base);
    const float4* Dp = (const float4*)(depth + (size_t)b * HW + base);

    const int nvec = pixPerBlock / 4;  // 1024 -> exactly 4 iters/thread
#pragma unroll
    for (int it = 0; it < 4; ++it) {
        const int i = tid + it * 256;
        float4 r  = Rp[i];
        float4 g  = Gp[i];
        float4 bl = Bp[i];
        float4 d  = Dp[i];

        float il0 = 0.2f * r.x + 0.7f * g.x + 0.1f * bl.x;
        float il1 = 0.2f * r.y + 0.7f * g.y + 0.1f * bl.y;
        float il2 = 0.2f * r.z + 0.7f * g.z + 0.1f * bl.z;
        float il3 = 0.2f * r.w + 0.7f * g.w + 0.1f * bl.w;

        // depth is exactly k/255, k in [0,255] -> no clamp needed
        int k0 = (int)(d.x * 255.0f + 0.5f);
        int k1 = (int)(d.y * 255.0f + 0.5f);
        int k2 = (int)(d.z * 255.0f + 0.5f);
        int k3 = (int)(d.w * 255.0f + 0.5f);

        unsigned long long v0 = (1ull << CNT_SHIFT) | (unsigned long long)(unsigned int)(il0 * FIX_SCALE + 0.5f);
        unsigned long long v1 = (1ull << CNT_SHIFT) | (unsigned long long)(unsigned int)(il1 * FIX_SCALE + 0.5f);
        unsigned long long v2 = (1ull << CNT_SHIFT) | (unsigned long long)(unsigned int)(il2 * FIX_SCALE + 0.5f);
        unsigned long long v3 = (1ull << CNT_SHIFT) | (unsigned long long)(unsigned int)(il3 * FIX_SCALE + 0.5f);

        atomicAdd(&s_hist[wave][k0], v0);
        atomicAdd(&s_hist[wave][k1], v1);
        atomicAdd(&s_hist[wave][k2], v2);
        atomicAdd(&s_hist[wave][k3], v3);
    }
    (void)nvec;
    __syncthreads();

    // fold sub-histograms; one atomic per bin per block, each cell on its own
    // 64B cache line -> 2048 independent lines, ~64 atomics deep each
    for (int k = tid; k < NBINS; k += 256) {
        unsigned long long v = s_hist[0][k] + s_hist[1][k] + s_hist[2][k] + s_hist[3][k];
        atomicAdd(&hist[(size_t)(b * NBINS + k) * CELL_STRIDE], v);
    }
}

__global__ __launch_bounds__(1024) void finalize_kernel(
    const unsigned long long* __restrict__ hist,  // padded
    float* __restrict__ out)
{
    __shared__ float mean[BATCH * NBINS];  // 32 KB
    __shared__ float wsum[16];

    const int tid = threadIdx.x;

    for (int p = tid; p < BATCH * NBINS; p += 1024) {
        unsigned long long v = hist[(size_t)p * CELL_STRIDE];
        float s = (float)(v & SUM_MASK) * (1.0f / FIX_SCALE);
        float c = (float)(unsigned int)(v >> CNT_SHIFT);
        mean[p] = s / c;
    }
    __syncthreads();

    float acc = 0.0f;
    for (int p = tid; p < BATCH * NBINS; p += 1024) {
        int k = p & (NBINS - 1);
        if (k < NBINS - 1) {
            float d = mean[p] - mean[p + 1];
            acc += fmaxf(d, 0.0f);
        }
    }

    for (int off = 32; off > 0; off >>= 1)
        acc += __shfl_down(acc, off, 64);
    if ((tid & 63) == 0) wsum[tid >> 6] = acc;
    __syncthreads();
    if (tid == 0) {
        float total = 0.0f;
        for (int w = 0; w < 16; ++w) total += wsum[w];
        out[0] = total / (255.0f * (float)BATCH);
    }
}

extern "C" void kernel_launch(void* const* d_in, const int* in_sizes, int n_in,
                              void* d_out, int out_size, void* d_ws, size_t ws_size,
                              hipStream_t stream)
{
    const float* img   = (const float*)d_in[0];
    const float* depth = (const float*)d_in[1];
    float* out = (float*)d_out;
    unsigned long long* hist = (unsigned long long*)d_ws;

    // zero padded accumulators every call (128 KB)
    hipMemsetAsync(d_ws, 0,
                   (size_t)BATCH * NBINS * CELL_STRIDE * sizeof(unsigned long long),
                   stream);

    hist_kernel<<<BATCH * BLOCKS_PER_SAMPLE, 256, 0, stream>>>(img, depth, hist);
    finalize_kernel<<<1, 1024, 0, stream>>>(hist, out);
}

// Round 8
// 31.912 us; speedup vs baseline: 6.3200x; 1.5465x over previous
//
#include <hip/hip_runtime.h>

#define NBINS 256
#define BATCH 32
#define HW (512 * 512)
#define NSUB 4                 // per-wave sub-histograms (256 threads = 4 waves)
#define BLOCKS_PER_SAMPLE 64
#define NBLOCKS (BATCH * BLOCKS_PER_SAMPLE)  // 2048

// Packed fixed-point histogram cell:
//   bits [0:43]  : sum of illum * 2^24   (per-sample max 2^42)
//   bits [44:63] : count                 (per-sample max 2^18)
#define CNT_SHIFT 44
#define SUM_MASK ((1ull << CNT_SHIFT) - 1)
#define FIX_SCALE 16777216.0f  // 2^24

__global__ __launch_bounds__(256) void hist_kernel(
    const float* __restrict__ img,              // [B,3,H,W]
    const float* __restrict__ depth,            // [B,1,H,W]
    unsigned long long* __restrict__ partials)  // [NBLOCKS, NBINS] plain-stored
{
    __shared__ unsigned long long s_hist[NSUB][NBINS];  // 8 KB

    const int tid  = threadIdx.x;
    const int wave = tid >> 6;

    for (int i = tid; i < NSUB * NBINS; i += 256)
        ((unsigned long long*)s_hist)[i] = 0ull;
    __syncthreads();

    const int b     = blockIdx.x / BLOCKS_PER_SAMPLE;
    const int chunk = blockIdx.x % BLOCKS_PER_SAMPLE;
    const int pixPerBlock = HW / BLOCKS_PER_SAMPLE;  // 4096
    const int base = chunk * pixPerBlock;

    const float4* Rp = (const float4*)(img + (size_t)b * 3 * HW + 0 * HW + base);
    const float4* Gp = (const float4*)(img + (size_t)b * 3 * HW + 1 * HW + base);
    const float4* Bp = (const float4*)(img + (size_t)b * 3 * HW + 2 * HW + base);
    const float4* Dp = (const float4*)(depth + (size_t)b * HW + base);

    const int nvec = pixPerBlock / 4;  // 1024 float4s per block
    for (int i = tid; i < nvec; i += 256) {
        float4 r  = Rp[i];
        float4 g  = Gp[i];
        float4 bl = Bp[i];
        float4 d  = Dp[i];

        float il0 = 0.2f * r.x + 0.7f * g.x + 0.1f * bl.x;
        float il1 = 0.2f * r.y + 0.7f * g.y + 0.1f * bl.y;
        float il2 = 0.2f * r.z + 0.7f * g.z + 0.1f * bl.z;
        float il3 = 0.2f * r.w + 0.7f * g.w + 0.1f * bl.w;

        int k0 = (int)(d.x * 255.0f + 0.5f);
        int k1 = (int)(d.y * 255.0f + 0.5f);
        int k2 = (int)(d.z * 255.0f + 0.5f);
        int k3 = (int)(d.w * 255.0f + 0.5f);
        k0 = min(max(k0, 0), NBINS - 1);
        k1 = min(max(k1, 0), NBINS - 1);
        k2 = min(max(k2, 0), NBINS - 1);
        k3 = min(max(k3, 0), NBINS - 1);

        unsigned long long v0 = (1ull << CNT_SHIFT) | (unsigned long long)(unsigned int)(il0 * FIX_SCALE + 0.5f);
        unsigned long long v1 = (1ull << CNT_SHIFT) | (unsigned long long)(unsigned int)(il1 * FIX_SCALE + 0.5f);
        unsigned long long v2 = (1ull << CNT_SHIFT) | (unsigned long long)(unsigned int)(il2 * FIX_SCALE + 0.5f);
        unsigned long long v3 = (1ull << CNT_SHIFT) | (unsigned long long)(unsigned int)(il3 * FIX_SCALE + 0.5f);

        atomicAdd(&s_hist[wave][k0], v0);
        atomicAdd(&s_hist[wave][k1], v1);
        atomicAdd(&s_hist[wave][k2], v2);
        atomicAdd(&s_hist[wave][k3], v3);
    }
    __syncthreads();

    // fold sub-histograms; PLAIN coalesced store of this block's partial
    // (no global atomics, no zeroed workspace needed)
    for (int k = tid; k < NBINS; k += 256) {
        unsigned long long v = s_hist[0][k] + s_hist[1][k] + s_hist[2][k] + s_hist[3][k];
        partials[(size_t)blockIdx.x * NBINS + k] = v;
    }
}

// one block per sample: sum 64 partials, means, relu-diff, per-sample loss
__global__ __launch_bounds__(256) void reduce_kernel(
    const unsigned long long* __restrict__ partials,  // [NBLOCKS, NBINS]
    float* __restrict__ sampleLoss)                   // [BATCH]
{
    __shared__ float mean[NBINS];
    __shared__ float wsum[4];

    const int b   = blockIdx.x;
    const int tid = threadIdx.x;  // = bin index

    unsigned long long acc = 0ull;
    const unsigned long long* p = partials + (size_t)b * BLOCKS_PER_SAMPLE * NBINS;
#pragma unroll 8
    for (int j = 0; j < BLOCKS_PER_SAMPLE; ++j)
        acc += p[(size_t)j * NBINS + tid];  // 256 threads -> 2KB coalesced rows

    float s = (float)(acc & SUM_MASK) * (1.0f / FIX_SCALE);
    float c = (float)(unsigned int)(acc >> CNT_SHIFT);
    mean[tid] = s / c;
    __syncthreads();

    float v = 0.0f;
    if (tid < NBINS - 1)
        v = fmaxf(mean[tid] - mean[tid + 1], 0.0f);

    for (int off = 32; off > 0; off >>= 1)
        v += __shfl_down(v, off, 64);
    if ((tid & 63) == 0) wsum[tid >> 6] = v;
    __syncthreads();
    if (tid == 0)
        sampleLoss[b] = wsum[0] + wsum[1] + wsum[2] + wsum[3];
}

__global__ __launch_bounds__(64) void final_kernel(
    const float* __restrict__ sampleLoss,  // [BATCH]
    float* __restrict__ out)
{
    const int tid = threadIdx.x;
    float v = (tid < BATCH) ? sampleLoss[tid] : 0.0f;
    for (int off = 32; off > 0; off >>= 1)
        v += __shfl_down(v, off, 64);
    if (tid == 0)
        out[0] = v / (255.0f * (float)BATCH);
}

extern "C" void kernel_launch(void* const* d_in, const int* in_sizes, int n_in,
                              void* d_out, int out_size, void* d_ws, size_t ws_size,
                              hipStream_t stream)
{
    const float* img   = (const float*)d_in[0];
    const float* depth = (const float*)d_in[1];
    float* out = (float*)d_out;

    unsigned long long* partials = (unsigned long long*)d_ws;  // 4 MB
    float* sampleLoss = (float*)((char*)d_ws + (size_t)NBLOCKS * NBINS * sizeof(unsigned long long));

    // no memset: partials and sampleLoss are fully overwritten every call
    hist_kernel<<<NBLOCKS, 256, 0, stream>>>(img, depth, partials);
    reduce_kernel<<<BATCH, 256, 0, stream>>>(partials, sampleLoss);
    final_kernel<<<1, 64, 0, stream>>>(sampleLoss, out);
}

// Round 9
// 30.645 us; speedup vs baseline: 6.5813x; 1.0413x over previous
//
#include <hip/hip_runtime.h>

#define NBINS 256
#define BATCH 32
#define HW (512 * 512)
#define NSUB 4                 // per-wave sub-histograms (256 threads = 4 waves)
#define BLOCKS_PER_SAMPLE 64
#define NBLOCKS (BATCH * BLOCKS_PER_SAMPLE)  // 2048

// Packed fixed-point u32 histogram cell (per block, so bounds are small):
//   bits [0:18]  : sum of illum * 2^6   (block max 4096*64 = 2^18)
//   bits [19:31] : count                (block max 4096 = 2^12; field holds 8191)
// Worst case 4096<<19 + 2^18 < 2^32 -> no overflow.
#define CNT_SHIFT32 19
#define SUM_MASK32 ((1u << CNT_SHIFT32) - 1)
#define FIX_SCALE32 64.0f  // 2^6
// loss quantization error ~3e-6 << 7.5e-5 threshold (see analysis)

__global__ __launch_bounds__(256) void hist_kernel(
    const float* __restrict__ img,        // [B,3,H,W]
    const float* __restrict__ depth,      // [B,1,H,W]
    unsigned int* __restrict__ partials)  // [NBLOCKS, NBINS] plain-stored
{
    __shared__ unsigned int s_hist[NSUB][NBINS];  // 4 KB

    const int tid  = threadIdx.x;
    const int wave = tid >> 6;

    for (int i = tid; i < NSUB * NBINS; i += 256)
        ((unsigned int*)s_hist)[i] = 0u;
    __syncthreads();

    const int b     = blockIdx.x / BLOCKS_PER_SAMPLE;
    const int chunk = blockIdx.x % BLOCKS_PER_SAMPLE;
    const int pixPerBlock = HW / BLOCKS_PER_SAMPLE;  // 4096
    const int base = chunk * pixPerBlock;

    const float4* Rp = (const float4*)(img + (size_t)b * 3 * HW + 0 * HW + base);
    const float4* Gp = (const float4*)(img + (size_t)b * 3 * HW + 1 * HW + base);
    const float4* Bp = (const float4*)(img + (size_t)b * 3 * HW + 2 * HW + base);
    const float4* Dp = (const float4*)(depth + (size_t)b * HW + base);

    const int nvec = pixPerBlock / 4;  // 1024 float4s per block
    for (int i = tid; i < nvec; i += 256) {
        float4 r  = Rp[i];
        float4 g  = Gp[i];
        float4 bl = Bp[i];
        float4 d  = Dp[i];

        float il0 = 0.2f * r.x + 0.7f * g.x + 0.1f * bl.x;
        float il1 = 0.2f * r.y + 0.7f * g.y + 0.1f * bl.y;
        float il2 = 0.2f * r.z + 0.7f * g.z + 0.1f * bl.z;
        float il3 = 0.2f * r.w + 0.7f * g.w + 0.1f * bl.w;

        int k0 = (int)(d.x * 255.0f + 0.5f);
        int k1 = (int)(d.y * 255.0f + 0.5f);
        int k2 = (int)(d.z * 255.0f + 0.5f);
        int k3 = (int)(d.w * 255.0f + 0.5f);
        k0 = min(max(k0, 0), NBINS - 1);
        k1 = min(max(k1, 0), NBINS - 1);
        k2 = min(max(k2, 0), NBINS - 1);
        k3 = min(max(k3, 0), NBINS - 1);

        unsigned int v0 = (1u << CNT_SHIFT32) | (unsigned int)(il0 * FIX_SCALE32 + 0.5f);
        unsigned int v1 = (1u << CNT_SHIFT32) | (unsigned int)(il1 * FIX_SCALE32 + 0.5f);
        unsigned int v2 = (1u << CNT_SHIFT32) | (unsigned int)(il2 * FIX_SCALE32 + 0.5f);
        unsigned int v3 = (1u << CNT_SHIFT32) | (unsigned int)(il3 * FIX_SCALE32 + 0.5f);

        // native ds_add_u32: single-bank 32-bit RMW (was 2-bank u64)
        atomicAdd(&s_hist[wave][k0], v0);
        atomicAdd(&s_hist[wave][k1], v1);
        atomicAdd(&s_hist[wave][k2], v2);
        atomicAdd(&s_hist[wave][k3], v3);
    }
    __syncthreads();

    // fold sub-histograms; plain coalesced store (fits u32: block-level bounds)
    for (int k = tid; k < NBINS; k += 256) {
        unsigned int v = s_hist[0][k] + s_hist[1][k] + s_hist[2][k] + s_hist[3][k];
        partials[(size_t)blockIdx.x * NBINS + k] = v;
    }
}

// one block per sample: unpack+sum 64 partials, means, relu-diff, per-sample loss
__global__ __launch_bounds__(256) void reduce_kernel(
    const unsigned int* __restrict__ partials,  // [NBLOCKS, NBINS]
    float* __restrict__ sampleLoss)             // [BATCH]
{
    __shared__ float mean[NBINS];
    __shared__ float wsum[4];

    const int b   = blockIdx.x;
    const int tid = threadIdx.x;  // = bin index

    unsigned int acc_s = 0u, acc_c = 0u;
    const unsigned int* p = partials + (size_t)b * BLOCKS_PER_SAMPLE * NBINS;
#pragma unroll 8
    for (int j = 0; j < BLOCKS_PER_SAMPLE; ++j) {
        unsigned int v = p[(size_t)j * NBINS + tid];  // coalesced 1KB rows
        acc_s += v & SUM_MASK32;   // sample total < 2^24
        acc_c += v >> CNT_SHIFT32; // sample total < 2^18
    }

    mean[tid] = ((float)acc_s * (1.0f / FIX_SCALE32)) / (float)acc_c;
    __syncthreads();

    float v = 0.0f;
    if (tid < NBINS - 1)
        v = fmaxf(mean[tid] - mean[tid + 1], 0.0f);

    for (int off = 32; off > 0; off >>= 1)
        v += __shfl_down(v, off, 64);
    if ((tid & 63) == 0) wsum[tid >> 6] = v;
    __syncthreads();
    if (tid == 0)
        sampleLoss[b] = wsum[0] + wsum[1] + wsum[2] + wsum[3];
}

__global__ __launch_bounds__(64) void final_kernel(
    const float* __restrict__ sampleLoss,  // [BATCH]
    float* __restrict__ out)
{
    const int tid = threadIdx.x;
    float v = (tid < BATCH) ? sampleLoss[tid] : 0.0f;
    for (int off = 32; off > 0; off >>= 1)
        v += __shfl_down(v, off, 64);
    if (tid == 0)
        out[0] = v / (255.0f * (float)BATCH);
}

extern "C" void kernel_launch(void* const* d_in, const int* in_sizes, int n_in,
                              void* d_out, int out_size, void* d_ws, size_t ws_size,
                              hipStream_t stream)
{
    const float* img   = (const float*)d_in[0];
    const float* depth = (const float*)d_in[1];
    float* out = (float*)d_out;

    unsigned int* partials = (unsigned int*)d_ws;  // 2 MB
    float* sampleLoss = (float*)((char*)d_ws + (size_t)NBLOCKS * NBINS * sizeof(unsigned int));

    // no memset: partials and sampleLoss fully overwritten every call
    hist_kernel<<<NBLOCKS, 256, 0, stream>>>(img, depth, partials);
    reduce_kernel<<<BATCH, 256, 0, stream>>>(partials, sampleLoss);
    final_kernel<<<1, 64, 0, stream>>>(sampleLoss, out);
}